// Round 8
// baseline (79.204 us; speedup 1.0000x reference)
//
#include <hip/hip_runtime.h>
#include <math.h>

// AWLoss closed-form: f = 24 - (0.5/511^2) * sum_c S1_c^2 / S2_c
// S1 = sum wgt*Re(F), S2 = sum wgt*|F|^2 over half-spectrum k1 in [0,511),
// k2 in [0,256), wgt = 1 for k2==0 else 2, F = conj(X)Y / |X|^2
// (1e-9 pre-whitening is < 1e-12 relative to |X|^2 ~ 1e4 -> dropped).
// X = DFT2(pad(target)), Y = DFT2(pad(recon)), pad offset 127.
//
// Round-8 structure: both stages are canonical-GEMM-shaped. The twiddle tile
// (16KB) is staged into LDS once per BLOCK (double-buffered, shared by the 4
// waves) instead of streamed per-wave from L2 -- rounds 4/6/7 proved the
// per-wave stream is latency-serialized at 1 wave/SIMD no matter how the
// registers are arranged. Per-wave data (input rows / x1t frags) stays
// register-pinned.

#define NCH 48
#define PADOFF 127
#define TWO_PI_F 6.283185307179586f

typedef float f32x4 __attribute__((ext_vector_type(4)));
typedef short s16x8 __attribute__((ext_vector_type(8)));
typedef unsigned short u16;

union frag_u { u16 u[8]; s16x8 v; };

__device__ __forceinline__ u16 f2bf(float f) {
    union { float f; unsigned u; } x; x.f = f;
    unsigned r = x.u + 0x7FFFu + ((x.u >> 16) & 1u);
    return (u16)(r >> 16);
}

#define MFMA16(A, B, C) __builtin_amdgcn_mfma_f32_16x16x32_bf16(A, B, C, 0, 0, 0)

// ---------------- setup: twiddle fragment table + acc zero ----------------
// w2f : fragments [kt(32)][c(2)][kk(8)][lane(64)][j(8)] bf16
//       element: tw((16kt + (l&15)) * (32kk + 8(l>>4) + j + 127) mod 511),
//       c=0 cos, c=1 sin; row k1==511 zeroed.
__global__ __launch_bounds__(256) void setup(u16* __restrict__ w2f,
                                             float* __restrict__ sacc) {
    __shared__ float cs[511], sn[511];
    int tid = threadIdx.x;
    for (int i = tid; i < 511; i += 256) {
        float a = -TWO_PI_F * (float)i / 511.0f;
        cs[i] = cosf(a);
        sn[i] = sinf(a);
    }
    __syncthreads();

    int i = blockIdx.x * 256 + tid;      // i < 262144
    int j = i & 7, l = (i >> 3) & 63, kk = (i >> 9) & 7;
    int c = (i >> 12) & 1, kt = i >> 13;
    int k1 = 16 * kt + (l & 15);
    u16 v = 0;
    if (k1 < 511) {
        int n = 32 * kk + 8 * (l >> 4) + j;
        int p = (k1 * (n + PADOFF)) % 511;
        v = f2bf(c ? sn[p] : cs[p]);
    }
    w2f[i] = v;
    if (blockIdx.x == 0 && tid < 2 * NCH) sacc[tid] = 0.0f;
}

// ---------------- stage 1: DFT along W (MFMA, LDS-staged twiddles) ----------------
// X1[n1][k2] = sum_b src[n1][b] * W[b][k2]; x1t[lc*4 + tsel*2 + c][k2][n1] bf16.
// grid = cc*4 blocks x 4 waves; wave task = (img, mp): rows 32mp..32mp+31.
__global__ __launch_bounds__(256, 1) void stage1(const float* __restrict__ target,
                                                 const float* __restrict__ recon,
                                                 const u16* __restrict__ w2f,
                                                 u16* __restrict__ x1t,
                                                 int c0) {
    int tid = threadIdx.x;
    int w = tid >> 6, l = tid & 63;
    int lm = l & 15, lh = l >> 4;
    int flat = blockIdx.x * 4 + w;       // [0, 2cc*8)
    int img = flat >> 3;
    int mp  = flat & 7;
    int lc = img >> 1;
    int tsel = img & 1;
    const float* src = (tsel == 0 ? target : recon) + (size_t)(c0 + lc) * 65536;

    __shared__ u16 lbuf[2][8192];        // 32 KiB double buffer, one 16KB t-tile each

    // A fragments: 32 rows (2 sub-tiles of 16), full K=256, f32 -> bf16
    frag_u af[2][8];
    #pragma unroll
    for (int a = 0; a < 2; ++a) {
        const float* ap = src + (size_t)(32 * mp + 16 * a + lm) * 256 + 8 * lh;
        #pragma unroll
        for (int kk = 0; kk < 8; ++kk) {
            float4 v0 = *(const float4*)(ap + 32 * kk);
            float4 v1 = *(const float4*)(ap + 32 * kk + 4);
            af[a][kk].u[0] = f2bf(v0.x); af[a][kk].u[1] = f2bf(v0.y);
            af[a][kk].u[2] = f2bf(v0.z); af[a][kk].u[3] = f2bf(v0.w);
            af[a][kk].u[4] = f2bf(v1.x); af[a][kk].u[5] = f2bf(v1.y);
            af[a][kk].u[6] = f2bf(v1.z); af[a][kk].u[7] = f2bf(v1.w);
        }
    }
    #pragma unroll
    for (int a = 0; a < 2; ++a)
        #pragma unroll
        for (int kk = 0; kk < 8; ++kk)
            asm volatile("" : "+v"(af[a][kk].v));

    u16* chdst = x1t + (size_t)(lc * 4 + tsel * 2) * 65536;

    // prologue: stage t=0
    s16x8 sr[4];
    #pragma unroll
    for (int i = 0; i < 4; ++i)
        sr[i] = *(const s16x8*)(w2f + (size_t)(tid + 256 * i) * 8);
    #pragma unroll
    for (int i = 0; i < 4; ++i)
        *(s16x8*)&lbuf[0][(tid + 256 * i) * 8] = sr[i];
    __syncthreads();

    for (int t = 0; t < 16; ++t) {
        int p = t & 1;
        if (t < 15) {                    // issue next tile's loads (lands under MFMA)
            const u16* gp = w2f + (size_t)(t + 1) * 8192;
            #pragma unroll
            for (int i = 0; i < 4; ++i)
                sr[i] = *(const s16x8*)(gp + (tid + 256 * i) * 8);
        }
        f32x4 ac0 = {0,0,0,0}, as0 = {0,0,0,0}, ac1 = {0,0,0,0}, as1 = {0,0,0,0};
        #pragma unroll
        for (int kk = 0; kk < 8; ++kk) {
            s16x8 bc = *(const s16x8*)&lbuf[p][kk * 512 + l * 8];
            s16x8 bs = *(const s16x8*)&lbuf[p][4096 + kk * 512 + l * 8];
            ac0 = MFMA16(af[0][kk].v, bc, ac0);
            as0 = MFMA16(af[0][kk].v, bs, as0);
            ac1 = MFMA16(af[1][kk].v, bc, ac1);
            as1 = MFMA16(af[1][kk].v, bs, as1);
        }
        // D element (m = 4lh+r, n = lm): n1 = 32mp+16a+4lh+r, k2 = 16t+lm
        {
            ushort4 o0, o1;
            o0.x = f2bf(ac0[0]); o0.y = f2bf(ac0[1]);
            o0.z = f2bf(ac0[2]); o0.w = f2bf(ac0[3]);
            o1.x = f2bf(as0[0]); o1.y = f2bf(as0[1]);
            o1.z = f2bf(as0[2]); o1.w = f2bf(as0[3]);
            size_t off = (size_t)(16 * t + lm) * 256 + 32 * mp + 4 * lh;
            *(ushort4*)(chdst + off)         = o0;
            *(ushort4*)(chdst + 65536 + off) = o1;
            o0.x = f2bf(ac1[0]); o0.y = f2bf(ac1[1]);
            o0.z = f2bf(ac1[2]); o0.w = f2bf(ac1[3]);
            o1.x = f2bf(as1[0]); o1.y = f2bf(as1[1]);
            o1.z = f2bf(as1[2]); o1.w = f2bf(as1[3]);
            *(ushort4*)(chdst + off + 16)         = o0;
            *(ushort4*)(chdst + 65536 + off + 16) = o1;
        }
        __syncthreads();                 // all waves done reading lbuf[p]
        if (t < 15) {
            #pragma unroll
            for (int i = 0; i < 4; ++i)
                *(s16x8*)&lbuf[p ^ 1][(tid + 256 * i) * 8] = sr[i];
            __syncthreads();             // lbuf[p^1] ready
        }
    }
}

// ---------------- stage 2: DFT along H (MFMA, LDS-staged twiddles) + reduce ----------------
// grid = cc*4 blocks x 4 waves; wave task = (lc, t). x1t frags register-pinned;
// the 4 waves share each kt's 16KB w2f tile from LDS (double-buffered).
__global__ __launch_bounds__(256, 1) void stage2(const u16* __restrict__ x1t,
                                                 const u16* __restrict__ w2f,
                                                 float* __restrict__ sacc,
                                                 int c0) {
    int tid = threadIdx.x;
    int w = tid >> 6, l = tid & 63;
    int lm = l & 15, lh = l >> 4;
    int task = blockIdx.x * 4 + w;      // [0, cc*16)
    int lc = task >> 4;
    int t  = task & 15;

    __shared__ u16 lbuf[2][8192];       // 32 KiB double buffer

    const u16* base = x1t + (size_t)(4 * lc) * 65536;   // planes Xr,Xi,Yr,Yi
    size_t roff = (size_t)(16 * t + lm) * 256 + 8 * lh;

    // B fragments: this wave's (ch, k2-tile), full K, register-pinned
    s16x8 ar[8], ai[8], br[8], bi[8];
    #pragma unroll
    for (int kk = 0; kk < 8; ++kk) {
        size_t off = roff + 32 * kk;
        ar[kk] = *(const s16x8*)(base + off);
        ai[kk] = *(const s16x8*)(base + 65536 + off);
        br[kk] = *(const s16x8*)(base + 131072 + off);
        bi[kk] = *(const s16x8*)(base + 196608 + off);
    }
    #pragma unroll
    for (int kk = 0; kk < 8; ++kk)
        asm volatile("" : "+v"(ar[kk]), "+v"(ai[kk]), "+v"(br[kk]), "+v"(bi[kk]));

    int k2 = 16 * t + lm;
    float wgt = (k2 == 0) ? 1.f : 2.f;
    float s1 = 0.f, s2 = 0.f;

    // prologue: stage kt=0
    s16x8 sr[4];
    #pragma unroll
    for (int i = 0; i < 4; ++i)
        sr[i] = *(const s16x8*)(w2f + (size_t)(tid + 256 * i) * 8);
    #pragma unroll
    for (int i = 0; i < 4; ++i)
        *(s16x8*)&lbuf[0][(tid + 256 * i) * 8] = sr[i];
    __syncthreads();

    for (int kt = 0; kt < 32; ++kt) {
        int p = kt & 1;
        if (kt < 31) {                   // issue next tile's loads
            const u16* gp = w2f + (size_t)(kt + 1) * 8192;
            #pragma unroll
            for (int i = 0; i < 4; ++i)
                sr[i] = *(const s16x8*)(gp + (tid + 256 * i) * 8);
        }
        f32x4 crr = {0,0,0,0}, cii = {0,0,0,0}, cri = {0,0,0,0}, cir = {0,0,0,0};
        f32x4 drr = {0,0,0,0}, dii = {0,0,0,0}, dri = {0,0,0,0}, dir = {0,0,0,0};
        #pragma unroll
        for (int kk = 0; kk < 8; ++kk) {
            s16x8 wr = *(const s16x8*)&lbuf[p][kk * 512 + l * 8];
            s16x8 wi = *(const s16x8*)&lbuf[p][4096 + kk * 512 + l * 8];
            crr = MFMA16(wr, ar[kk], crr);
            cii = MFMA16(wi, ai[kk], cii);
            cri = MFMA16(wr, ai[kk], cri);
            cir = MFMA16(wi, ar[kk], cir);
            drr = MFMA16(wr, br[kk], drr);
            dii = MFMA16(wi, bi[kk], dii);
            dri = MFMA16(wr, bi[kk], dri);
            dir = MFMA16(wi, br[kk], dir);
        }
        #pragma unroll
        for (int r = 0; r < 4; ++r) {
            int k1 = 16 * kt + 4 * lh + r;
            float wg2 = (k1 < 511) ? wgt : 0.f;
            float Xr = crr[r] - cii[r], Xi = cri[r] + cir[r];
            float Yr = drr[r] - dii[r], Yi = dri[r] + dir[r];
            float Pr = Xr * Yr + Xi * Yi;
            float Pi = Xr * Yi - Xi * Yr;
            float Q  = Xr * Xr + Xi * Xi;
            float inv = 1.0f / (Q * Q + 1e-30f);
            s1 += wg2 * Pr * Q * inv;
            s2 += wg2 * (Pr * Pr + Pi * Pi) * inv;
        }
        __syncthreads();                 // all waves done reading lbuf[p]
        if (kt < 31) {
            #pragma unroll
            for (int i = 0; i < 4; ++i)
                *(s16x8*)&lbuf[p ^ 1][(tid + 256 * i) * 8] = sr[i];
            __syncthreads();             // lbuf[p^1] ready
        }
    }

    #pragma unroll
    for (int off = 32; off > 0; off >>= 1) {
        s1 += __shfl_down(s1, off);
        s2 += __shfl_down(s2, off);
    }
    if (l == 0) {
        atomicAdd(&sacc[c0 + lc], s1);
        atomicAdd(&sacc[NCH + c0 + lc], s2);
    }
}

__global__ void finalize(const float* __restrict__ s, float* __restrict__ out) {
    int t = threadIdx.x;
    float v = 0.f;
    if (t < NCH) {
        float s1 = s[t], s2 = s[NCH + t];
        v = (s2 != 0.f) ? (s1 * s1) / s2 : 0.f;
    }
    for (int off = 32; off > 0; off >>= 1) v += __shfl_down(v, off);
    if (t == 0) out[0] = 24.0f - 0.5f * v / 261121.0f;
}

// ---------------- launch ----------------
extern "C" void kernel_launch(void* const* d_in, const int* in_sizes, int n_in,
                              void* d_out, int out_size, void* d_ws, size_t ws_size,
                              hipStream_t stream) {
    const float* recon  = (const float*)d_in[0];
    const float* target = (const float*)d_in[1];
    float* out = (float*)d_out;
    char* ws = (char*)d_ws;

    const size_t OFF_W2F = 0;                        // 524288 B
    const size_t OFF_S   = OFF_W2F + 524288;         // 512 B
    const size_t OFF_X1  = OFF_S + 512;

    u16*   w2f  = (u16*)(ws + OFF_W2F);
    float* sacc = (float*)(ws + OFF_S);
    u16*   x1t  = (u16*)(ws + OFF_X1);

    const size_t perch = 4ull * 65536 * 2;           // 512 KiB per channel
    size_t avail = (ws_size > OFF_X1) ? ws_size - OFF_X1 : 0;
    int chunk = (int)(avail / perch);
    if (chunk > NCH) chunk = NCH;
    if (chunk < 1) chunk = 1;

    setup<<<dim3(1024), dim3(256), 0, stream>>>(w2f, sacc);

    for (int c0 = 0; c0 < NCH; c0 += chunk) {
        int cc = (NCH - c0 < chunk) ? (NCH - c0) : chunk;
        stage1<<<dim3(cc * 4), dim3(256), 0, stream>>>(target, recon, w2f, x1t, c0);
        stage2<<<dim3(cc * 4), dim3(256), 0, stream>>>(x1t, w2f, sacc, c0);
    }
    finalize<<<dim3(1), dim3(64), 0, stream>>>(sacc, out);
}